// Round 8
// baseline (109.779 us; speedup 1.0000x reference)
//
#include <hip/hip_runtime.h>
#include <hip/hip_fp16.h>

// SpMM: out[r, :] = sum_{e: row[e]==r} vals[e] * embeds[col[e], :]
// N_NODES=50000, N_EDGES=800000, D=64. row_idx is SORTED.
//
// R7 post-mortem: fp16 halved gather bytes but barely moved time -> spmm is
// issue/VALU-bound (cvt+fma chains, 24-op butterfly epilogue, clamp waste),
// not cache-BW-bound. R8: lane=feature layout.
//   - One wave per row; lane f owns feature f. NO shuffle reduce, single
//     coalesced 256B store per row.
//   - Gather: tbl[c*64+lane], 2B/lane x 64 = one 128B line per edge (same
//     line-request count as R7; memory load unchanged).
//   - Metadata scalarized via readfirstlane -> col/val loads go down the
//     scalar path; gather base computed on SALU. Per-edge VALU ~2 (cvt+fmac).
//   - 4 edges per chunk, 4 independent gathers in flight; tail padded v=0.
//   - Every row written (deg-0 rows store 0) -> no output memset.
// fp16 table: absmax 0.0625 measured (threshold 0.29).

constexpr int N_NODES = 50000;
constexpr int N_EDGES = 800000;
constexpr int D_FEAT  = 64;

using half4 = __attribute__((ext_vector_type(4))) _Float16;
using fvec4 = __attribute__((ext_vector_type(4))) float;

// d_ws layout
constexpr size_t WS_ROWPTR_OFF = 0;          // (N_NODES+1) ints (~200 KB)
constexpr size_t WS_TBL_OFF    = 1u << 20;   // 50000*64 halves = 6.4 MB

constexpr int ROWPTR_BLOCKS  = (N_EDGES + 255) / 256;        // 3125
constexpr int CONVERT_BLOCKS = (N_NODES * 16 + 255) / 256;   // 3125

__global__ __launch_bounds__(256) void prep_kernel(
    const int*   __restrict__ row_idx,
    const float* __restrict__ embeds,
    int*         __restrict__ row_ptr,
    _Float16*    __restrict__ tbl)
{
    if (blockIdx.x < ROWPTR_BLOCKS) {
        const int e = blockIdx.x * 256 + threadIdx.x;
        if (e >= N_EDGES) return;
        const int r     = row_idx[e];
        const int rprev = (e == 0) ? -1 : row_idx[e - 1];
        for (int q = rprev + 1; q <= r; ++q) row_ptr[q] = e;   // fills empty rows
        if (e == N_EDGES - 1) {
            for (int q = r + 1; q <= N_NODES; ++q) row_ptr[q] = N_EDGES;
        }
    } else {
        // fp32 -> fp16 convert, row-major (row = 128B = one cache line).
        const int t = (blockIdx.x - ROWPTR_BLOCKS) * 256 + threadIdx.x;
        if (t >= N_NODES * 16) return;
        const fvec4 v = __builtin_nontemporal_load(((const fvec4*)embeds) + t);
        half4 hv;
        hv[0] = (_Float16)v.x; hv[1] = (_Float16)v.y;
        hv[2] = (_Float16)v.z; hv[3] = (_Float16)v.w;
        ((half4*)tbl)[t] = hv;
    }
}

__global__ __launch_bounds__(256) void gcn_spmm_kernel(
    const int*      __restrict__ row_ptr,
    const int*      __restrict__ col_idx,
    const float*    __restrict__ vals,
    const _Float16* __restrict__ tbl,
    float*          __restrict__ out)
{
    const int row = blockIdx.x * 4 + (threadIdx.x >> 6);  // one wave per row
    if (row >= N_NODES) return;
    const int lane = threadIdx.x & 63;                    // feature index

    const int es = __builtin_amdgcn_readfirstlane(row_ptr[row]);
    const int ee = __builtin_amdgcn_readfirstlane(row_ptr[row + 1]);

    float acc = 0.f;

    for (int e = es; e < ee; e += 4) {
        // Tail padding: clamp indices, zero the padded vals.
        const int i1 = (e + 1 < ee) ? e + 1 : ee - 1;
        const int i2 = (e + 2 < ee) ? e + 2 : ee - 1;
        const int i3 = (e + 3 < ee) ? e + 3 : ee - 1;

        const int c0 = __builtin_amdgcn_readfirstlane(col_idx[e]);
        const int c1 = __builtin_amdgcn_readfirstlane(col_idx[i1]);
        const int c2 = __builtin_amdgcn_readfirstlane(col_idx[i2]);
        const int c3 = __builtin_amdgcn_readfirstlane(col_idx[i3]);

        const float v0 = vals[e];
        const float v1 = (e + 1 < ee) ? vals[i1] : 0.f;
        const float v2 = (e + 2 < ee) ? vals[i2] : 0.f;
        const float v3 = (e + 3 < ee) ? vals[i3] : 0.f;

        // 4 independent one-line (128B) gathers in flight.
        const float g0 = (float)tbl[c0 * 64 + lane];
        const float g1 = (float)tbl[c1 * 64 + lane];
        const float g2 = (float)tbl[c2 * 64 + lane];
        const float g3 = (float)tbl[c3 * 64 + lane];

        acc += v0 * g0;
        acc += v1 * g1;
        acc += v2 * g2;
        acc += v3 * g3;
    }

    // Lane f owns feature f: single coalesced 256B wave store, no reduce.
    __builtin_nontemporal_store(acc, out + row * D_FEAT + lane);
}

extern "C" void kernel_launch(void* const* d_in, const int* in_sizes, int n_in,
                              void* d_out, int out_size, void* d_ws, size_t ws_size,
                              hipStream_t stream) {
    const int*   row_idx = (const int*)  d_in[0];
    const int*   col_idx = (const int*)  d_in[1];
    const float* vals    = (const float*)d_in[2];
    const float* embeds  = (const float*)d_in[3];
    float*       out     = (float*)      d_out;

    char* ws = (char*)d_ws;
    int*      row_ptr = (int*)     (ws + WS_ROWPTR_OFF);
    _Float16* tbl     = (_Float16*)(ws + WS_TBL_OFF);

    prep_kernel<<<ROWPTR_BLOCKS + CONVERT_BLOCKS, 256, 0, stream>>>(
        row_idx, embeds, row_ptr, tbl);

    // One wave per row, 4 rows per block.
    gcn_spmm_kernel<<<(N_NODES + 3) / 4, 256, 0, stream>>>(
        row_ptr, col_idx, vals, tbl, out);
}

// Round 9
// 98.866 us; speedup vs baseline: 1.1104x; 1.1104x over previous
//
#include <hip/hip_runtime.h>

// SpMM: out[r, :] = sum_{e: row[e]==r} vals[e] * embeds[col[e], :]
// N_NODES=50000, N_EDGES=800000, D=64. row_idx is SORTED.
//
// R8 post-mortem: lane=feature cut in-flight lines 16->4 and regressed.
// Model: spmm is bound by L2-miss serve (~2 TB/s) on COMPULSORY gather-line
// traffic (caches cold each iter: harness re-poisons 268MB ws). fp16 rows =
// 1 line/row -> ~53 MB/iter compulsory. R9: int8 per-row-scaled table ->
// row = 64B, 2 rows per 128B line, table 3.2MB, distinct-line footprint
// halves. Keep R7's MLP structure (8 edge slots x 8B lanes, 2 independent
// 8-line gathers in flight, butterfly epilogue).
//   decode: f = (float)(int8) * scale[col];  w = val*scale folded per edge.
//   accuracy: per-row scale, rel err <= 1/254 of row-max -> est absmax ~0.1
//   (threshold 0.29; fp16 measured 0.0625).

constexpr int N_NODES = 50000;
constexpr int N_EDGES = 800000;
constexpr int D_FEAT  = 64;

using fvec4 = __attribute__((ext_vector_type(4))) float;

// d_ws layout
constexpr size_t WS_ROWPTR_OFF = 0;          // (N_NODES+1) ints (~200 KB)
constexpr size_t WS_TBL_OFF    = 1u << 20;   // 50000*64 int8 = 3.2 MB
constexpr size_t WS_SCALE_OFF  = 5u << 20;   // 50000 floats (~200 KB)

constexpr int ROWPTR_BLOCKS = (N_EDGES + 255) / 256;   // 3125
constexpr int QUANT_BLOCKS  = (N_NODES + 3) / 4;       // 12500 (1 wave/row)

__global__ __launch_bounds__(256) void prep_kernel(
    const int*   __restrict__ row_idx,
    const float* __restrict__ embeds,
    int*         __restrict__ row_ptr,
    signed char* __restrict__ tbl,
    float*       __restrict__ scales)
{
    if (blockIdx.x < ROWPTR_BLOCKS) {
        const int e = blockIdx.x * 256 + threadIdx.x;
        if (e >= N_EDGES) return;
        const int r     = row_idx[e];
        const int rprev = (e == 0) ? -1 : row_idx[e - 1];
        for (int q = rprev + 1; q <= r; ++q) row_ptr[q] = e;   // fills empty rows
        if (e == N_EDGES - 1) {
            for (int q = r + 1; q <= N_NODES; ++q) row_ptr[q] = N_EDGES;
        }
    } else {
        // int8 per-row quantize: one wave per row, lane = feature.
        const int r = (blockIdx.x - ROWPTR_BLOCKS) * 4 + (threadIdx.x >> 6);
        if (r >= N_NODES) return;
        const int lane = threadIdx.x & 63;
        const float x = embeds[r * D_FEAT + lane];   // coalesced 256B
        float m = fabsf(x);
#pragma unroll
        for (int mask = 1; mask < 64; mask <<= 1)
            m = fmaxf(m, __shfl_xor(m, mask));
        const float qs = (m > 0.f) ? 127.f / m : 0.f;
        const int   q  = (int)rintf(x * qs);         // in [-127, 127]
        tbl[r * D_FEAT + lane] = (signed char)q;     // 64B wave store
        if (lane == 0) scales[r] = (m > 0.f) ? m / 127.f : 0.f;
    }
}

__global__ __launch_bounds__(256) void gcn_spmm_kernel(
    const int*         __restrict__ row_ptr,
    const int*         __restrict__ col_idx,
    const float*       __restrict__ vals,
    const signed char* __restrict__ tbl,
    const float*       __restrict__ scales,
    float*             __restrict__ out)
{
    const int row = blockIdx.x * 4 + (threadIdx.x >> 6);  // one wave per row
    if (row >= N_NODES) return;

    const int lane = threadIdx.x & 63;
    const int g    = lane >> 3;          // edge slot (8 per wave-load)
    const int h    = lane & 7;           // byte-octet: features [h*8, h*8+8)

    const int es = row_ptr[row];
    const int ee = row_ptr[row + 1];

    const uint2* __restrict__ tbl8 = (const uint2*)tbl;   // 8B chunk, 8 per row

    float acc[8] = {0.f, 0.f, 0.f, 0.f, 0.f, 0.f, 0.f, 0.f};

    for (int base = es; base < ee; base += 16) {
        const int e0 = base + g;
        const int e1 = base + 8 + g;
        const int i0 = (e0 < ee) ? e0 : ee - 1;        // clamp (in-bounds)
        const int i1 = (e1 < ee) ? e1 : ee - 1;
        const int c0 = col_idx[i0];
        const int c1 = col_idx[i1];
        const float v0 = (e0 < ee) ? vals[i0] : 0.f;
        const float v1 = (e1 < ee) ? vals[i1] : 0.f;
        // 2 independent gathers; 8 edges x 64B each (2 table rows per line).
        const uint2 q0 = tbl8[c0 * 8 + h];
        const uint2 q1 = tbl8[c1 * 8 + h];
        const float w0 = v0 * scales[c0];              // 200KB table, L2-hot
        const float w1 = v1 * scales[c1];
#pragma unroll
        for (int k = 0; k < 4; ++k) {
            acc[k]     += w0 * (float)(signed char)((q0.x >> (8 * k)) & 0xff);
            acc[4 + k] += w0 * (float)(signed char)((q0.y >> (8 * k)) & 0xff);
            acc[k]     += w1 * (float)(signed char)((q1.x >> (8 * k)) & 0xff);
            acc[4 + k] += w1 * (float)(signed char)((q1.y >> (8 * k)) & 0xff);
        }
    }

    // Reduce over the 8 edge slots (lane bits 3..5).
#pragma unroll
    for (int mask = 8; mask <= 32; mask <<= 1) {
#pragma unroll
        for (int i = 0; i < 8; ++i) acc[i] += __shfl_xor(acc[i], mask);
    }

    if (g == 0) {
        // Lane h owns features [h*8, h*8+8) of the 256B output row.
        fvec4* o4 = (fvec4*)(out + row * D_FEAT + h * 8);
        fvec4 lo, hi;
        lo.x = acc[0]; lo.y = acc[1]; lo.z = acc[2]; lo.w = acc[3];
        hi.x = acc[4]; hi.y = acc[5]; hi.z = acc[6]; hi.w = acc[7];
        __builtin_nontemporal_store(lo, o4);
        __builtin_nontemporal_store(hi, o4 + 1);
    }
}

extern "C" void kernel_launch(void* const* d_in, const int* in_sizes, int n_in,
                              void* d_out, int out_size, void* d_ws, size_t ws_size,
                              hipStream_t stream) {
    const int*   row_idx = (const int*)  d_in[0];
    const int*   col_idx = (const int*)  d_in[1];
    const float* vals    = (const float*)d_in[2];
    const float* embeds  = (const float*)d_in[3];
    float*       out     = (float*)      d_out;

    char* ws = (char*)d_ws;
    int*         row_ptr = (int*)        (ws + WS_ROWPTR_OFF);
    signed char* tbl     = (signed char*)(ws + WS_TBL_OFF);
    float*       scales  = (float*)      (ws + WS_SCALE_OFF);

    prep_kernel<<<ROWPTR_BLOCKS + QUANT_BLOCKS, 256, 0, stream>>>(
        row_idx, embeds, row_ptr, tbl, scales);

    // One wave per row, 4 rows per block.
    gcn_spmm_kernel<<<(N_NODES + 3) / 4, 256, 0, stream>>>(
        row_ptr, col_idx, vals, tbl, scales, out);
}

// Round 10
// 98.456 us; speedup vs baseline: 1.1150x; 1.0042x over previous
//
#include <hip/hip_runtime.h>

// SpMM: out[r, :] = sum_{e: row[e]==r} vals[e] * embeds[col[e], :]
// N_NODES=50000, N_EDGES=800000, D=64. row_idx is SORTED.
//
// R9 post-mortem: int8 halved bytes, gained only ~1us -> spmm is latency-rate
// bound: trips/wave x chain-latency / lines-in-flight. R10 attacks trips and
// MLP with the same int8 table:
//   - 16 edge slots (g=lane>>2) x 4 lanes (h=lane&3, 16B chunk): one dwordx4
//     gather = 16 edges x 64B. Unroll x2 -> 32 edges/iter, so Poisson(16)
//     degrees finish in ONE iteration 99.96% of the time (R9 needed a serial
//     2nd trip for ~half the rows). Up to 32 lines in flight (R9: 16).
//   - Reduce-scatter butterfly epilogue (15 shfl vs 64): each lane ends with
//     ONE feature f = h*16+g; single all-lane 4B NT store per row.
//   - Every row written (deg-0 rows store 0) -> no output memset.
// accuracy: per-row int8 scale, measured absmax 0.088 (threshold 0.29).

constexpr int N_NODES = 50000;
constexpr int N_EDGES = 800000;
constexpr int D_FEAT  = 64;

using uvec4 = __attribute__((ext_vector_type(4))) unsigned int;
using fvec4 = __attribute__((ext_vector_type(4))) float;

// d_ws layout
constexpr size_t WS_ROWPTR_OFF = 0;          // (N_NODES+1) ints (~200 KB)
constexpr size_t WS_TBL_OFF    = 1u << 20;   // 50000*64 int8 = 3.2 MB
constexpr size_t WS_SCALE_OFF  = 5u << 20;   // 50000 floats (~200 KB)

constexpr int ROWPTR_BLOCKS = (N_EDGES + 255) / 256;   // 3125
constexpr int QUANT_BLOCKS  = (N_NODES + 3) / 4;       // 12500 (1 wave/row)

__global__ __launch_bounds__(256) void prep_kernel(
    const int*   __restrict__ row_idx,
    const float* __restrict__ embeds,
    int*         __restrict__ row_ptr,
    signed char* __restrict__ tbl,
    float*       __restrict__ scales)
{
    if (blockIdx.x < ROWPTR_BLOCKS) {
        const int e = blockIdx.x * 256 + threadIdx.x;
        if (e >= N_EDGES) return;
        const int r     = row_idx[e];
        const int rprev = (e == 0) ? -1 : row_idx[e - 1];
        for (int q = rprev + 1; q <= r; ++q) row_ptr[q] = e;   // fills empty rows
        if (e == N_EDGES - 1) {
            for (int q = r + 1; q <= N_NODES; ++q) row_ptr[q] = N_EDGES;
        }
    } else {
        // int8 per-row quantize: one wave per row, lane = feature.
        const int r = (blockIdx.x - ROWPTR_BLOCKS) * 4 + (threadIdx.x >> 6);
        if (r >= N_NODES) return;
        const int lane = threadIdx.x & 63;
        const float x = embeds[r * D_FEAT + lane];   // coalesced 256B
        float m = fabsf(x);
#pragma unroll
        for (int mask = 1; mask < 64; mask <<= 1)
            m = fmaxf(m, __shfl_xor(m, mask));
        const float qs = (m > 0.f) ? 127.f / m : 0.f;
        const int   q  = (int)rintf(x * qs);         // in [-127, 127]
        tbl[r * D_FEAT + lane] = (signed char)q;     // 64B wave store
        if (lane == 0) scales[r] = (m > 0.f) ? m / 127.f : 0.f;
    }
}

__global__ __launch_bounds__(256) void gcn_spmm_kernel(
    const int*         __restrict__ row_ptr,
    const int*         __restrict__ col_idx,
    const float*       __restrict__ vals,
    const signed char* __restrict__ tbl,
    const float*       __restrict__ scales,
    float*             __restrict__ out)
{
    const int row = blockIdx.x * 4 + (threadIdx.x >> 6);  // one wave per row
    if (row >= N_NODES) return;

    const int lane = threadIdx.x & 63;
    const int g    = lane >> 2;          // edge slot (16 per wave-load)
    const int h    = lane & 3;           // 16B chunk: features [h*16, h*16+16)

    const int es = __builtin_amdgcn_readfirstlane(row_ptr[row]);
    const int ee = __builtin_amdgcn_readfirstlane(row_ptr[row + 1]);

    const uvec4* __restrict__ tbl16 = (const uvec4*)tbl;   // 4 uvec4 per row

    float acc[16];
#pragma unroll
    for (int i = 0; i < 16; ++i) acc[i] = 0.f;

    for (int base = es; base < ee; base += 32) {
        const int e0 = base + g;
        const int e1 = base + 16 + g;
        const int i0 = (e0 < ee) ? e0 : ee - 1;        // clamp (in-bounds)
        const int i1 = (e1 < ee) ? e1 : ee - 1;
        const int c0 = col_idx[i0];
        const int c1 = col_idx[i1];
        const float v0 = (e0 < ee) ? vals[i0] : 0.f;
        const float v1 = (e1 < ee) ? vals[i1] : 0.f;
        // 2 independent 16-edge gathers (dwordx4), up to 32 lines in flight.
        const uvec4 q0 = tbl16[c0 * 4 + h];
        const uvec4 q1 = tbl16[c1 * 4 + h];
        const float w0 = v0 * scales[c0];              // 200KB table, L2-hot
        const float w1 = v1 * scales[c1];
#pragma unroll
        for (int wd = 0; wd < 4; ++wd) {
#pragma unroll
            for (int b = 0; b < 4; ++b) {
                acc[wd * 4 + b] +=
                    w0 * (float)(signed char)((q0[wd] >> (8 * b)) & 0xff);
                acc[wd * 4 + b] +=
                    w1 * (float)(signed char)((q1[wd] >> (8 * b)) & 0xff);
            }
        }
    }

    // Reduce-scatter butterfly over the 16 edge slots (lane bits 2..5).
    // After stage k the live-value count halves; lane ends with the single
    // feature j == g (index arithmetic: j = 8*g3+4*g2+2*g1+g0 = g).
    float a8[8];
    {
        const int b = g & 1;
#pragma unroll
        for (int j = 0; j < 8; ++j) {
            const float send = b ? acc[2 * j] : acc[2 * j + 1];
            const float keep = b ? acc[2 * j + 1] : acc[2 * j];
            a8[j] = keep + __shfl_xor(send, 4);
        }
    }
    float a4[4];
    {
        const int b = (g >> 1) & 1;
#pragma unroll
        for (int j = 0; j < 4; ++j) {
            const float send = b ? a8[2 * j] : a8[2 * j + 1];
            const float keep = b ? a8[2 * j + 1] : a8[2 * j];
            a4[j] = keep + __shfl_xor(send, 8);
        }
    }
    float a2[2];
    {
        const int b = (g >> 2) & 1;
#pragma unroll
        for (int j = 0; j < 2; ++j) {
            const float send = b ? a4[2 * j] : a4[2 * j + 1];
            const float keep = b ? a4[2 * j + 1] : a4[2 * j];
            a2[j] = keep + __shfl_xor(send, 16);
        }
    }
    float a1;
    {
        const int b = (g >> 3) & 1;
        const float send = b ? a2[0] : a2[1];
        const float keep = b ? a2[1] : a2[0];
        a1 = keep + __shfl_xor(send, 32);
    }

    // Lane (g,h) owns feature h*16+g; all 64 lanes hit one 256B span.
    __builtin_nontemporal_store(a1, out + row * D_FEAT + h * 16 + g);
}

extern "C" void kernel_launch(void* const* d_in, const int* in_sizes, int n_in,
                              void* d_out, int out_size, void* d_ws, size_t ws_size,
                              hipStream_t stream) {
    const int*   row_idx = (const int*)  d_in[0];
    const int*   col_idx = (const int*)  d_in[1];
    const float* vals    = (const float*)d_in[2];
    const float* embeds  = (const float*)d_in[3];
    float*       out     = (float*)      d_out;

    char* ws = (char*)d_ws;
    int*         row_ptr = (int*)        (ws + WS_ROWPTR_OFF);
    signed char* tbl     = (signed char*)(ws + WS_TBL_OFF);
    float*       scales  = (float*)      (ws + WS_SCALE_OFF);

    prep_kernel<<<ROWPTR_BLOCKS + QUANT_BLOCKS, 256, 0, stream>>>(
        row_idx, embeds, row_ptr, tbl, scales);

    // One wave per row, 4 rows per block.
    gcn_spmm_kernel<<<(N_NODES + 3) / 4, 256, 0, stream>>>(
        row_ptr, col_idx, vals, tbl, scales, out);
}